// Round 1
// baseline (1225.622 us; speedup 1.0000x reference)
//
#include <hip/hip_runtime.h>
#include <stdint.h>

#define DEVI __device__ __forceinline__

typedef unsigned short u16;
typedef __attribute__((ext_vector_type(8))) short short8;
typedef __attribute__((ext_vector_type(4))) float f32x4;
typedef __attribute__((ext_vector_type(16))) float f32x16;

DEVI u16 f2bf(float f) {
  union { float f; uint32_t u; } v; v.f = f;
  return (u16)((v.u + 0x7fffu + ((v.u >> 16) & 1u)) >> 16);
}
DEVI float sigm(float x) { return 1.0f / (1.0f + __expf(-x)); }
DEVI float tanh_f(float x) {
  x = fminf(fmaxf(x, -15.0f), 15.0f);
  float e = __expf(2.0f * x);
  return (e - 1.0f) / (e + 1.0f);
}

// ---------------------------------------------------------------- prep
__global__ void prep_kernel(
    const float* __restrict__ W_ih0, const float* __restrict__ W_hh0,
    const float* __restrict__ W_ih1, const float* __restrict__ W_hh1,
    const float* __restrict__ W_enc, const float* __restrict__ W_dec,
    const float* __restrict__ W_out, const float* __restrict__ embed,
    const float* __restrict__ hs_pad,
    const float* __restrict__ b_ih0, const float* __restrict__ b_hh0,
    const float* __restrict__ b_ih1, const float* __restrict__ b_hh1,
    const float* __restrict__ b_out,
    u16* __restrict__ Wih0b, u16* __restrict__ Whh0b,
    u16* __restrict__ Wih1b, u16* __restrict__ Whh1b,
    u16* __restrict__ Wencb, u16* __restrict__ Wdecb,
    u16* __restrict__ embedb, u16* __restrict__ hsb,
    u16* __restrict__ Wshufb,
    float* __restrict__ bsum0, float* __restrict__ bsum1, float* __restrict__ boutp)
{
  const int c1 = 1048576, c2 = 2097152, c3 = 3145728, c4 = 4194304;
  const int c5 = 4456448, c6 = 4718592, c7 = 5025792, c8 = 6664192;
  const int c9 = 6991872, c10 = 6993920, c11 = 6995968, c12 = 6996608;
  for (int i = blockIdx.x * blockDim.x + threadIdx.x; i < c12; i += gridDim.x * blockDim.x) {
    if (i < c1)       Wih0b[i]      = f2bf(W_ih0[i]);
    else if (i < c2)  Whh0b[i - c1] = f2bf(W_hh0[i - c1]);
    else if (i < c3)  Wih1b[i - c2] = f2bf(W_ih1[i - c2]);
    else if (i < c4)  Whh1b[i - c3] = f2bf(W_hh1[i - c3]);
    else if (i < c5)  Wencb[i - c4] = f2bf(W_enc[i - c4]);
    else if (i < c6)  Wdecb[i - c5] = f2bf(W_dec[i - c5]);
    else if (i < c7)  embedb[i - c6] = f2bf(embed[i - c6]);
    else if (i < c8)  hsb[i - c7]   = f2bf(hs_pad[i - c7]);
    else if (i < c9) {
      // W_out pre-shuffled for 32x32x16 B-fragments: [32 kc][20 tile][64 lane][8]
      int e = i - c8;
      int kc = e / 10240, r = e % 10240;
      int tile = r >> 9, r2 = r & 511;
      int lane = r2 >> 3, ii = r2 & 7;
      int n = tile * 32 + (lane & 31);
      int k = kc * 16 + ((lane >> 5) << 3) + ii;
      Wshufb[e] = (n < 600) ? f2bf(W_out[n * 512 + k]) : (u16)0;
    }
    else if (i < c10) { int n = i - c9;  bsum0[n] = b_ih0[n] + b_hh0[n]; }
    else if (i < c11) { int n = i - c10; bsum1[n] = b_ih1[n] + b_hh1[n]; }
    else              { int n = i - c11; boutp[n] = (n < 600) ? b_out[n] : 0.0f; }
  }
}

// ------------------------------------------------- generic 64x64 MFMA GEMM
// out[M][N] = A[M][512] @ B[N][512]^T (+bias). mode 1: A-row = embedb[ys[b*64+u]], m=u*16+b
__global__ __launch_bounds__(256) void gemm_bf16(
    const u16* __restrict__ A, const u16* __restrict__ B,
    const int* __restrict__ ys, const float* __restrict__ bias,
    float* __restrict__ out, int N, int mode)
{
  int tid = threadIdx.x, wv = tid >> 6, l = tid & 63;
  int m0 = blockIdx.x * 64, n0 = blockIdx.y * 64;
  int row = m0 + wv * 16 + (l & 15);
  const u16* arow;
  if (mode == 1) { int uu = row >> 4, bb = row & 15; arow = A + (size_t)ys[bb * 64 + uu] * 512; }
  else           arow = A + (size_t)row * 512;
  int kof = (l >> 4) * 8;
  arow += kof;
  const u16* br = B + (size_t)(n0 + (l & 15)) * 512 + kof;
  f32x4 a0 = {0.f,0.f,0.f,0.f}, a1 = a0, a2 = a0, a3 = a0;
  for (int kk = 0; kk < 512; kk += 32) {
    short8 av = *(const short8*)(arow + kk);
    short8 b0 = *(const short8*)(br + kk);
    short8 b1 = *(const short8*)(br + 8192 + kk);
    short8 b2 = *(const short8*)(br + 16384 + kk);
    short8 b3 = *(const short8*)(br + 24576 + kk);
    a0 = __builtin_amdgcn_mfma_f32_16x16x32_bf16(av, b0, a0, 0, 0, 0);
    a1 = __builtin_amdgcn_mfma_f32_16x16x32_bf16(av, b1, a1, 0, 0, 0);
    a2 = __builtin_amdgcn_mfma_f32_16x16x32_bf16(av, b2, a2, 0, 0, 0);
    a3 = __builtin_amdgcn_mfma_f32_16x16x32_bf16(av, b3, a3, 0, 0, 0);
  }
  int col = l & 15, rb = m0 + wv * 16 + (l >> 4) * 4;
  f32x4 accs[4] = {a0, a1, a2, a3};
#pragma unroll
  for (int g = 0; g < 4; ++g) {
    int n = n0 + g * 16 + col;
    float bs = bias ? bias[n] : 0.0f;
#pragma unroll
    for (int i2 = 0; i2 < 4; ++i2)
      out[(size_t)(rb + i2) * N + n] = accs[g][i2] + bs;
  }
}

// ---------------------------------------------------------------- LSTM
#define NWG 32
DEVI void gridbar(int* bar, int seq) {
  __syncthreads();
  if (threadIdx.x == 0) {
    __threadfence();
    __hip_atomic_fetch_add(bar, 1, __ATOMIC_RELEASE, __HIP_MEMORY_SCOPE_AGENT);
    int target = NWG * seq;
    while (__hip_atomic_load(bar, __ATOMIC_ACQUIRE, __HIP_MEMORY_SCOPE_AGENT) < target)
      __builtin_amdgcn_s_sleep(16);
    __threadfence();
  }
  __syncthreads();
}

// 32 WGs x 256 thr. WG w owns hidden units [16w,16w+16). 2 grid barriers/step.
__global__ __launch_bounds__(256) void lstm_kernel(
    const float* __restrict__ Xg0,                 // [64][16][2048] (x@Wih0^T + b_ih0 + b_hh0)
    const u16* __restrict__ Whh0, const u16* __restrict__ Wih1, const u16* __restrict__ Whh1,
    const float* __restrict__ bsum1,
    u16* __restrict__ hbuf,                        // [2][16][1024] (h0 | h1), bf16
    u16* __restrict__ Hdec,                        // [64][16][512] bf16
    int* __restrict__ bar)
{
  __shared__ float red[16][256];
  int w = blockIdx.x, tid = threadIdx.x;
  int wv = tid >> 6, l = tid & 63;
  int lb = l & 15, kof = (l >> 4) * 8;
  int be = tid >> 4, je = tid & 15, jg = (w << 4) + je;
  const u16 *wh0[4], *wi1[4], *wh1[4];
#pragma unroll
  for (int g = 0; g < 4; ++g) {
    size_t nb = (size_t)(g * 512 + w * 16 + lb) * 512 + kof;
    wh0[g] = Whh0 + nb; wi1[g] = Wih1 + nb; wh1[g] = Whh1 + nb;
  }
  float c0 = 0.f, c1 = 0.f;
  int seq = 0;
  for (int t = 0; t < 64; ++t) {
    int pc = t & 1, po = pc ^ 1;
    { // phase A: gates0 = Xg0[t] + h0_old @ Whh0^T ; wave wv takes K slice [128wv,+128)
      f32x4 g0 = {0.f,0.f,0.f,0.f}, g1 = g0, g2 = g0, g3 = g0;
      const u16* hr = hbuf + po * 16384 + lb * 1024 + kof;
#pragma unroll
      for (int ks = 0; ks < 4; ++ks) {
        int kk = wv * 128 + ks * 32;
        short8 av = *(const short8*)(hr + kk);
        short8 b0 = *(const short8*)(wh0[0] + kk);
        short8 b1 = *(const short8*)(wh0[1] + kk);
        short8 b2 = *(const short8*)(wh0[2] + kk);
        short8 b3 = *(const short8*)(wh0[3] + kk);
        g0 = __builtin_amdgcn_mfma_f32_16x16x32_bf16(av, b0, g0, 0, 0, 0);
        g1 = __builtin_amdgcn_mfma_f32_16x16x32_bf16(av, b1, g1, 0, 0, 0);
        g2 = __builtin_amdgcn_mfma_f32_16x16x32_bf16(av, b2, g2, 0, 0, 0);
        g3 = __builtin_amdgcn_mfma_f32_16x16x32_bf16(av, b3, g3, 0, 0, 0);
      }
      int drb = (l >> 4) * 4;
      f32x4 gs[4] = {g0, g1, g2, g3};
#pragma unroll
      for (int g = 0; g < 4; ++g)
#pragma unroll
        for (int i2 = 0; i2 < 4; ++i2)
          red[wv * 4 + g][(drb + i2) * 16 + lb] = gs[g][i2];
    }
    __syncthreads();
    {
      float s0 = 0, s1 = 0, s2 = 0, s3 = 0;
#pragma unroll
      for (int v = 0; v < 4; ++v) {
        s0 += red[v * 4 + 0][be * 16 + je]; s1 += red[v * 4 + 1][be * 16 + je];
        s2 += red[v * 4 + 2][be * 16 + je]; s3 += red[v * 4 + 3][be * 16 + je];
      }
      const float* xg = Xg0 + (size_t)((t << 4) + be) * 2048 + jg;
      float gi = s0 + xg[0], gf = s1 + xg[512], gg = s2 + xg[1024], go = s3 + xg[1536];
      float I = sigm(gi), F = sigm(gf), G = tanh_f(gg), O = sigm(go);
      c0 = F * c0 + I * G;
      float h0 = O * tanh_f(c0);
      hbuf[pc * 16384 + be * 1024 + jg] = f2bf(h0);
    }
    gridbar(bar, ++seq);
    { // phase B: gates1 = h0_new @ Wih1^T + h1_old @ Whh1^T + bsum1 ; K=1024, wave slice [256wv,+256)
      f32x4 g0 = {0.f,0.f,0.f,0.f}, g1 = g0, g2 = g0, g3 = g0;
#pragma unroll
      for (int ks = 0; ks < 8; ++ks) {
        int kk = wv * 256 + ks * 32;
        int kfull = kk + kof;
        const u16* ha = (kfull < 512) ? (hbuf + pc * 16384 + lb * 1024 + kfull)
                                      : (hbuf + po * 16384 + lb * 1024 + kfull);
        short8 av = *(const short8*)ha;
        short8 b0, b1, b2, b3;
        if (kfull < 512) {
          b0 = *(const short8*)(wi1[0] + kk); b1 = *(const short8*)(wi1[1] + kk);
          b2 = *(const short8*)(wi1[2] + kk); b3 = *(const short8*)(wi1[3] + kk);
        } else {
          b0 = *(const short8*)(wh1[0] + kk - 512); b1 = *(const short8*)(wh1[1] + kk - 512);
          b2 = *(const short8*)(wh1[2] + kk - 512); b3 = *(const short8*)(wh1[3] + kk - 512);
        }
        g0 = __builtin_amdgcn_mfma_f32_16x16x32_bf16(av, b0, g0, 0, 0, 0);
        g1 = __builtin_amdgcn_mfma_f32_16x16x32_bf16(av, b1, g1, 0, 0, 0);
        g2 = __builtin_amdgcn_mfma_f32_16x16x32_bf16(av, b2, g2, 0, 0, 0);
        g3 = __builtin_amdgcn_mfma_f32_16x16x32_bf16(av, b3, g3, 0, 0, 0);
      }
      int drb = (l >> 4) * 4;
      f32x4 gs[4] = {g0, g1, g2, g3};
#pragma unroll
      for (int g = 0; g < 4; ++g)
#pragma unroll
        for (int i2 = 0; i2 < 4; ++i2)
          red[wv * 4 + g][(drb + i2) * 16 + lb] = gs[g][i2];
    }
    __syncthreads();
    {
      float s0 = 0, s1 = 0, s2 = 0, s3 = 0;
#pragma unroll
      for (int v = 0; v < 4; ++v) {
        s0 += red[v * 4 + 0][be * 16 + je]; s1 += red[v * 4 + 1][be * 16 + je];
        s2 += red[v * 4 + 2][be * 16 + je]; s3 += red[v * 4 + 3][be * 16 + je];
      }
      float gi = s0 + bsum1[jg],        gf = s1 + bsum1[512 + jg];
      float gg = s2 + bsum1[1024 + jg], go = s3 + bsum1[1536 + jg];
      float I = sigm(gi), F = sigm(gf), G = tanh_f(gg), O = sigm(go);
      c1 = F * c1 + I * G;
      float h1 = O * tanh_f(c1);
      u16 hb = f2bf(h1);
      hbuf[pc * 16384 + be * 1024 + 512 + jg] = hb;
      Hdec[(size_t)((t << 4) + be) * 512 + jg] = hb;
    }
    gridbar(bar, ++seq);
  }
}

// ---------------------------------------------------------------- joint
// out[b][t][u][n] = tanh(enc_p[b,t,:]+dec_p[u,b,:]) @ W_out^T + b_out
// M-tile 128 rows (8t x 16u), N padded 640, mfma 32x32x16, waves 2Mx4N
__global__ __launch_bounds__(512) void joint_kernel(
    const float* __restrict__ enc_p,   // [16*200][512]
    const float* __restrict__ dec_p,   // [64*16][512]  row = u*16+b
    const u16* __restrict__ Wshuf,     // [32][20][64][8] bf16
    const float* __restrict__ boutp,   // [640]
    float* __restrict__ out)
{
  __shared__ int4 wlds[2560];   // 40960 B: 2 k16-steps x 20 tiles x 64 lanes x 16B
  __shared__ int4 zlds[512];    // 8192 B:  z chunk 128 rows x 32 k, fragment-shuffled
  int bid = blockIdx.x;
  int b = bid / 100, rem = bid % 100;
  int tb = rem >> 2, ub = rem & 3;
  int tid = threadIdx.x, wv = tid >> 6, l = tid & 63;
  int mv = wv >> 2, nv = wv & 3;
  int ln31 = l & 31, lh = l >> 5;
  f32x16 acc[2][5];
#pragma unroll
  for (int j = 0; j < 5; ++j) {
    float bv = boutp[(nv * 5 + j) * 32 + ln31];
#pragma unroll
    for (int g = 0; g < 16; ++g) { acc[0][j][g] = bv; acc[1][j][g] = bv; }
  }
  int zr = tid & 127, zg = tid >> 7;
  const float* er = enc_p + (size_t)(b * 200 + tb * 8 + (zr >> 4)) * 512 + zg * 8;
  const float* dr = dec_p + (size_t)((ub * 16 + (zr & 15)) * 16 + b) * 512 + zg * 8;
  int zslot = ((zg >> 1) * 4 + (zr >> 5)) * 64 + ((zg & 1) << 5) + (zr & 31);
  const int4* gW = (const int4*)Wshuf;
  for (int c = 0; c < 16; ++c) {
    // stage W chunk (reg->LDS)
#pragma unroll
    for (int s = 0; s < 5; ++s)
      wlds[s * 512 + tid] = gW[c * 2560 + s * 512 + tid];
    // build z chunk: each thread 8 k-contiguous elems of one row
    {
      int k0 = c * 32;
      float4 e0 = *(const float4*)(er + k0);
      float4 e1 = *(const float4*)(er + k0 + 4);
      float4 d0 = *(const float4*)(dr + k0);
      float4 d1 = *(const float4*)(dr + k0 + 4);
      u16 q0 = f2bf(tanh_f(e0.x + d0.x)), q1 = f2bf(tanh_f(e0.y + d0.y));
      u16 q2 = f2bf(tanh_f(e0.z + d0.z)), q3 = f2bf(tanh_f(e0.w + d0.w));
      u16 q4 = f2bf(tanh_f(e1.x + d1.x)), q5 = f2bf(tanh_f(e1.y + d1.y));
      u16 q6 = f2bf(tanh_f(e1.z + d1.z)), q7 = f2bf(tanh_f(e1.w + d1.w));
      int4 pk;
      pk.x = (int)q0 | ((int)q1 << 16);
      pk.y = (int)q2 | ((int)q3 << 16);
      pk.z = (int)q4 | ((int)q5 << 16);
      pk.w = (int)q6 | ((int)q7 << 16);
      zlds[zslot] = pk;
    }
    __syncthreads();
#pragma unroll
    for (int ks = 0; ks < 2; ++ks) {
      short8 aA = *(const short8*)&zlds[(ks * 4 + 2 * mv + 0) * 64 + l];
      short8 aB = *(const short8*)&zlds[(ks * 4 + 2 * mv + 1) * 64 + l];
#pragma unroll
      for (int j = 0; j < 5; ++j) {
        short8 bw = *(const short8*)&wlds[(ks * 20 + nv * 5 + j) * 64 + l];
        acc[0][j] = __builtin_amdgcn_mfma_f32_32x32x16_bf16(aA, bw, acc[0][j], 0, 0, 0);
        acc[1][j] = __builtin_amdgcn_mfma_f32_32x32x16_bf16(aB, bw, acc[1][j], 0, 0, 0);
      }
    }
    __syncthreads();
  }
  // epilogue: D[row][col]: col = lane&31, row = (g&3) + 8*(g>>2) + 4*(lane>>5)
#pragma unroll
  for (int ab = 0; ab < 2; ++ab) {
#pragma unroll
    for (int j = 0; j < 5; ++j) {
      int n = (nv * 5 + j) * 32 + ln31;
      if (n < 600) {
        int rbase = mv * 64 + ab * 32 + 4 * lh;
#pragma unroll
        for (int g = 0; g < 16; ++g) {
          int r = rbase + (g & 3) + ((g >> 2) << 3);
          int tt = tb * 8 + (r >> 4), uu = ub * 16 + (r & 15);
          out[(size_t)((b * 200 + tt) * 64 + uu) * 600 + n] = acc[ab][j][g];
        }
      }
    }
  }
}

// ---------------------------------------------------------------- host
extern "C" void kernel_launch(void* const* d_in, const int* in_sizes, int n_in,
                              void* d_out, int out_size, void* d_ws, size_t ws_size,
                              hipStream_t stream) {
  const float* hs_pad = (const float*)d_in[0];
  const int*   ys     = (const int*)d_in[1];
  const float* embed  = (const float*)d_in[2];
  const float* W_ih0  = (const float*)d_in[3];
  const float* W_hh0  = (const float*)d_in[4];
  const float* b_ih0  = (const float*)d_in[5];
  const float* b_hh0  = (const float*)d_in[6];
  const float* W_ih1  = (const float*)d_in[7];
  const float* W_hh1  = (const float*)d_in[8];
  const float* b_ih1  = (const float*)d_in[9];
  const float* b_hh1  = (const float*)d_in[10];
  const float* W_enc  = (const float*)d_in[11];
  const float* b_enc  = (const float*)d_in[12];
  const float* W_dec  = (const float*)d_in[13];
  const float* W_out  = (const float*)d_in[14];
  const float* b_out  = (const float*)d_in[15];
  float* out = (float*)d_out;

  uint8_t* ws = (uint8_t*)d_ws;
  size_t off = 0;
  auto alloc = [&](size_t bytes) -> void* {
    void* p = ws + off;
    off = (off + bytes + 255) & ~(size_t)255;
    return p;
  };
  int* bar      = (int*)alloc(256);
  u16* hbuf     = (u16*)alloc(2 * 16 * 1024 * 2);        // 65536
  u16* Hdec     = (u16*)alloc(64 * 16 * 512 * 2);        // 1 MB
  float* Xg0    = (float*)alloc(1024 * 2048 * 4);        // 8 MB
  float* enc_p  = (float*)alloc(3200 * 512 * 4);         // 6.5 MB
  float* dec_p  = (float*)alloc(1024 * 512 * 4);         // 2 MB
  u16* Wih0b    = (u16*)alloc(2048 * 512 * 2);
  u16* Whh0b    = (u16*)alloc(2048 * 512 * 2);
  u16* Wih1b    = (u16*)alloc(2048 * 512 * 2);
  u16* Whh1b    = (u16*)alloc(2048 * 512 * 2);
  u16* Wencb    = (u16*)alloc(512 * 512 * 2);
  u16* Wdecb    = (u16*)alloc(512 * 512 * 2);
  u16* embedb   = (u16*)alloc(600 * 512 * 2);
  u16* hsb      = (u16*)alloc(3200 * 512 * 2);
  u16* Wshufb   = (u16*)alloc(32 * 20 * 64 * 8 * 2);
  float* bsum0  = (float*)alloc(2048 * 4);
  float* bsum1  = (float*)alloc(2048 * 4);
  float* boutp  = (float*)alloc(640 * 4);

  // zero barrier counters + hbuf (h/c initial state)
  (void)hipMemsetAsync(d_ws, 0, 65792, stream);

  prep_kernel<<<2048, 256, 0, stream>>>(
      W_ih0, W_hh0, W_ih1, W_hh1, W_enc, W_dec, W_out, embed, hs_pad,
      b_ih0, b_hh0, b_ih1, b_hh1, b_out,
      Wih0b, Whh0b, Wih1b, Whh1b, Wencb, Wdecb, embedb, hsb, Wshufb,
      bsum0, bsum1, boutp);

  // Xg0 = embed[ys] @ W_ih0^T + (b_ih0 + b_hh0), rows m = u*16+b
  dim3 g1(16, 32);
  gemm_bf16<<<g1, 256, 0, stream>>>(embedb, Wih0b, ys, bsum0, Xg0, 2048, 1);
  // enc_p = hs @ W_enc^T + b_enc
  dim3 g2(50, 8);
  gemm_bf16<<<g2, 256, 0, stream>>>(hsb, Wencb, nullptr, b_enc, enc_p, 512, 0);
  // sequential 2-layer LSTM
  lstm_kernel<<<NWG, 256, 0, stream>>>(Xg0, Whh0b, Wih1b, Whh1b, bsum1, hbuf, Hdec, bar);
  // dec_p = Hdec @ W_dec^T
  dim3 g3(16, 8);
  gemm_bf16<<<g3, 256, 0, stream>>>(Hdec, Wdecb, nullptr, nullptr, dec_p, 512, 0);
  // big fused joint
  joint_kernel<<<1600, 512, 0, stream>>>(enc_p, dec_p, Wshufb, boutp, out);
}

// Round 2
// 781.133 us; speedup vs baseline: 1.5690x; 1.5690x over previous
//
#include <hip/hip_runtime.h>
#include <stdint.h>

#define DEVI __device__ __forceinline__

typedef unsigned short u16;
typedef __attribute__((ext_vector_type(8))) short short8;
typedef __attribute__((ext_vector_type(4))) float f32x4;
typedef __attribute__((ext_vector_type(16))) float f32x16;

DEVI u16 f2bf(float f) {
  union { float f; uint32_t u; } v; v.f = f;
  return (u16)((v.u + 0x7fffu + ((v.u >> 16) & 1u)) >> 16);
}
DEVI float sigm(float x) { return 1.0f / (1.0f + __expf(-x)); }
DEVI float tanh_f(float x) {
  x = fminf(fmaxf(x, -15.0f), 15.0f);
  float e = __expf(2.0f * x);
  return (e - 1.0f) / (e + 1.0f);
}

// ---------------------------------------------------------------- prep
__global__ void prep_kernel(
    const float* __restrict__ W_ih0, const float* __restrict__ W_hh0,
    const float* __restrict__ W_ih1, const float* __restrict__ W_hh1,
    const float* __restrict__ W_enc, const float* __restrict__ W_dec,
    const float* __restrict__ W_out, const float* __restrict__ embed,
    const float* __restrict__ hs_pad,
    const float* __restrict__ b_ih0, const float* __restrict__ b_hh0,
    const float* __restrict__ b_ih1, const float* __restrict__ b_hh1,
    const float* __restrict__ b_out,
    u16* __restrict__ Wih0b, u16* __restrict__ Whh0b,
    u16* __restrict__ Wih1b, u16* __restrict__ Whh1b,
    u16* __restrict__ Wencb, u16* __restrict__ Wdecb,
    u16* __restrict__ embedb, u16* __restrict__ hsb,
    u16* __restrict__ Wshufb,
    float* __restrict__ bsum0, float* __restrict__ bsum1, float* __restrict__ boutp)
{
  const int c1 = 1048576, c2 = 2097152, c3 = 3145728, c4 = 4194304;
  const int c5 = 4456448, c6 = 4718592, c7 = 5025792, c8 = 6664192;
  const int c9 = 6991872, c10 = 6993920, c11 = 6995968, c12 = 6996608;
  for (int i = blockIdx.x * blockDim.x + threadIdx.x; i < c12; i += gridDim.x * blockDim.x) {
    if (i < c1)       Wih0b[i]      = f2bf(W_ih0[i]);
    else if (i < c2)  Whh0b[i - c1] = f2bf(W_hh0[i - c1]);
    else if (i < c3)  Wih1b[i - c2] = f2bf(W_ih1[i - c2]);
    else if (i < c4)  Whh1b[i - c3] = f2bf(W_hh1[i - c3]);
    else if (i < c5)  Wencb[i - c4] = f2bf(W_enc[i - c4]);
    else if (i < c6)  Wdecb[i - c5] = f2bf(W_dec[i - c5]);
    else if (i < c7)  embedb[i - c6] = f2bf(embed[i - c6]);
    else if (i < c8)  hsb[i - c7]   = f2bf(hs_pad[i - c7]);
    else if (i < c9) {
      // W_out pre-shuffled for 32x32x16 B-fragments: [32 kc][20 tile][64 lane][8]
      int e = i - c8;
      int kc = e / 10240, r = e % 10240;
      int tile = r >> 9, r2 = r & 511;
      int lane = r2 >> 3, ii = r2 & 7;
      int n = tile * 32 + (lane & 31);
      int k = kc * 16 + ((lane >> 5) << 3) + ii;
      Wshufb[e] = (n < 600) ? f2bf(W_out[n * 512 + k]) : (u16)0;
    }
    else if (i < c10) { int n = i - c9;  bsum0[n] = b_ih0[n] + b_hh0[n]; }
    else if (i < c11) { int n = i - c10; bsum1[n] = b_ih1[n] + b_hh1[n]; }
    else              { int n = i - c11; boutp[n] = (n < 600) ? b_out[n] : 0.0f; }
  }
}

// ------------------------------------------------- generic 64x64 MFMA GEMM
// out[M][N] = A[M][512] @ B[N][512]^T (+bias). mode 1: A-row = embedb[ys[b*64+u]], m=u*16+b
__global__ __launch_bounds__(256) void gemm_bf16(
    const u16* __restrict__ A, const u16* __restrict__ B,
    const int* __restrict__ ys, const float* __restrict__ bias,
    float* __restrict__ out, int N, int mode)
{
  int tid = threadIdx.x, wv = tid >> 6, l = tid & 63;
  int m0 = blockIdx.x * 64, n0 = blockIdx.y * 64;
  int row = m0 + wv * 16 + (l & 15);
  const u16* arow;
  if (mode == 1) { int uu = row >> 4, bb = row & 15; arow = A + (size_t)ys[bb * 64 + uu] * 512; }
  else           arow = A + (size_t)row * 512;
  int kof = (l >> 4) * 8;
  arow += kof;
  const u16* br = B + (size_t)(n0 + (l & 15)) * 512 + kof;
  f32x4 a0 = {0.f,0.f,0.f,0.f}, a1 = a0, a2 = a0, a3 = a0;
  for (int kk = 0; kk < 512; kk += 32) {
    short8 av = *(const short8*)(arow + kk);
    short8 b0 = *(const short8*)(br + kk);
    short8 b1 = *(const short8*)(br + 8192 + kk);
    short8 b2 = *(const short8*)(br + 16384 + kk);
    short8 b3 = *(const short8*)(br + 24576 + kk);
    a0 = __builtin_amdgcn_mfma_f32_16x16x32_bf16(av, b0, a0, 0, 0, 0);
    a1 = __builtin_amdgcn_mfma_f32_16x16x32_bf16(av, b1, a1, 0, 0, 0);
    a2 = __builtin_amdgcn_mfma_f32_16x16x32_bf16(av, b2, a2, 0, 0, 0);
    a3 = __builtin_amdgcn_mfma_f32_16x16x32_bf16(av, b3, a3, 0, 0, 0);
  }
  int col = l & 15, rb = m0 + wv * 16 + (l >> 4) * 4;
  f32x4 accs[4] = {a0, a1, a2, a3};
#pragma unroll
  for (int g = 0; g < 4; ++g) {
    int n = n0 + g * 16 + col;
    float bs = bias ? bias[n] : 0.0f;
#pragma unroll
    for (int i2 = 0; i2 < 4; ++i2)
      out[(size_t)(rb + i2) * N + n] = accs[g][i2] + bs;
  }
}

// ---------------------------------------------------------------- LSTM
// 96 WGs: bid 0..31 = layer 0 (16 units each), bid 32..95 = layer 1 (8 units each).
// Layer-pipelined: super-step s: L0 computes h0[s], L1 computes h1[s-1].
// One flag-array grid barrier per super-step (64 total).
#define L0WG 32
#define NWGT 96

DEVI void flagbar(int* flags, int bid, int tgt) {
  __syncthreads();
  if (threadIdx.x < 64) {
    int l = threadIdx.x;
    if (l == 0)
      __hip_atomic_store(flags + bid * 16, tgt, __ATOMIC_RELEASE, __HIP_MEMORY_SCOPE_AGENT);
    for (;;) {
      int a = __hip_atomic_load(flags + l * 16, __ATOMIC_RELAXED, __HIP_MEMORY_SCOPE_AGENT);
      int b = __hip_atomic_load(flags + (64 + l) * 16, __ATOMIC_RELAXED, __HIP_MEMORY_SCOPE_AGENT);
      if (__all(a >= tgt && b >= tgt)) break;
      __builtin_amdgcn_s_sleep(1);
    }
    __builtin_amdgcn_fence(__ATOMIC_ACQUIRE, "agent");
  }
  __syncthreads();
}

__global__ __launch_bounds__(256) void lstm_kernel(
    const float* __restrict__ Xg0,                 // [64][16][2048] (x@Wih0^T + bsum0)
    const u16* __restrict__ Whh0, const u16* __restrict__ Wih1, const u16* __restrict__ Whh1,
    const float* __restrict__ bsum1,
    u16* __restrict__ h0b, u16* __restrict__ h1b,  // each [2][16][512] bf16
    u16* __restrict__ Hdec,                        // [64][16][512] bf16
    int* __restrict__ flags)
{
  __shared__ float red[16][256];
  const int bid = blockIdx.x, tid = threadIdx.x;
  const int wv = tid >> 6, l = tid & 63;
  const int lb = l & 15, kof = (l >> 4) * 8;
  const int drb = (l >> 4) * 4;

  if (bid < L0WG) {
    // ---------------- layer 0: units [16*bid, 16*bid+16)
    const int be = tid >> 4, je = tid & 15, jg = (bid << 4) + je;
    // weights resident in registers for all 64 steps: wave wv owns k in [128wv,128wv+128)
    short8 breg[16];
#pragma unroll
    for (int g = 0; g < 4; ++g) {
      const u16* bp = Whh0 + (size_t)(g * 512 + bid * 16 + lb) * 512 + wv * 128 + kof;
#pragma unroll
      for (int ks = 0; ks < 4; ++ks)
        breg[g * 4 + ks] = *(const short8*)(bp + ks * 32);
    }
    float c0 = 0.f;
    for (int s = 0; s < 64; ++s) {
      const int rs = (s + 1) & 1, wsl = s & 1;
      f32x4 g0 = {0.f,0.f,0.f,0.f}, g1 = g0, g2 = g0, g3 = g0;
      const u16* hr = h0b + rs * 8192 + lb * 512 + wv * 128 + kof;
#pragma unroll
      for (int ks = 0; ks < 4; ++ks) {
        short8 av = *(const short8*)(hr + ks * 32);
        g0 = __builtin_amdgcn_mfma_f32_16x16x32_bf16(av, breg[0 * 4 + ks], g0, 0, 0, 0);
        g1 = __builtin_amdgcn_mfma_f32_16x16x32_bf16(av, breg[1 * 4 + ks], g1, 0, 0, 0);
        g2 = __builtin_amdgcn_mfma_f32_16x16x32_bf16(av, breg[2 * 4 + ks], g2, 0, 0, 0);
        g3 = __builtin_amdgcn_mfma_f32_16x16x32_bf16(av, breg[3 * 4 + ks], g3, 0, 0, 0);
      }
      f32x4 gs[4] = {g0, g1, g2, g3};
#pragma unroll
      for (int g = 0; g < 4; ++g)
#pragma unroll
        for (int i2 = 0; i2 < 4; ++i2)
          red[wv * 4 + g][(drb + i2) * 16 + lb] = gs[g][i2];
      __syncthreads();
      {
        float s0 = 0, s1 = 0, s2 = 0, s3 = 0;
#pragma unroll
        for (int v2 = 0; v2 < 4; ++v2) {
          s0 += red[v2 * 4 + 0][be * 16 + je]; s1 += red[v2 * 4 + 1][be * 16 + je];
          s2 += red[v2 * 4 + 2][be * 16 + je]; s3 += red[v2 * 4 + 3][be * 16 + je];
        }
        const float* xg = Xg0 + (size_t)((s << 4) + be) * 2048 + jg;
        float gi = s0 + xg[0], gf = s1 + xg[512], gg = s2 + xg[1024], go = s3 + xg[1536];
        float I = sigm(gi), F = sigm(gf), G = tanh_f(gg), O = sigm(go);
        c0 = F * c0 + I * G;
        float h0 = O * tanh_f(c0);
        h0b[wsl * 8192 + be * 512 + jg] = f2bf(h0);
      }
      flagbar(flags, bid, s + 1);
    }
  } else {
    // ---------------- layer 1: units [8v, 8v+8), v = bid-32
    const int v = bid - L0WG;
    // K=1024 (h0|h1): wave 0,1 -> Wih1 (k 0..511), wave 2,3 -> Whh1 (k 512..1023)
    const u16* base0 = (wv < 2) ? Wih1 : Whh1;
    const int kbase = (wv & 1) * 256;
    short8 breg[16];
#pragma unroll
    for (int tt = 0; tt < 2; ++tt) {
      int c = tt * 16 + lb, gate = c >> 3, du = c & 7;
      const u16* bp = base0 + (size_t)(gate * 512 + v * 8 + du) * 512 + kbase + kof;
#pragma unroll
      for (int ks = 0; ks < 8; ++ks)
        breg[tt * 8 + ks] = *(const short8*)(bp + ks * 32);
    }
    float bs0 = 0, bs1 = 0, bs2 = 0, bs3 = 0, c1 = 0.f;
    if (tid < 128) {
      int du = tid & 7, ju = v * 8 + du;
      bs0 = bsum1[ju]; bs1 = bsum1[512 + ju]; bs2 = bsum1[1024 + ju]; bs3 = bsum1[1536 + ju];
    }
    for (int s = 0; s <= 64; ++s) {
      if (s >= 1) {
        const int t = s - 1;
        const int rs0 = (s + 1) & 1;   // h0[s-1]
        const int rh1 = s & 1;         // h1[s-2]
        const int wh1s = (s + 1) & 1;  // h1[s-1]
        const u16* ha = ((wv < 2) ? (h0b + rs0 * 8192) : (h1b + rh1 * 8192))
                        + lb * 512 + kbase + kof;
        f32x4 g0 = {0.f,0.f,0.f,0.f}, g1 = g0;
#pragma unroll
        for (int ks = 0; ks < 8; ++ks) {
          short8 av = *(const short8*)(ha + ks * 32);
          g0 = __builtin_amdgcn_mfma_f32_16x16x32_bf16(av, breg[0 * 8 + ks], g0, 0, 0, 0);
          g1 = __builtin_amdgcn_mfma_f32_16x16x32_bf16(av, breg[1 * 8 + ks], g1, 0, 0, 0);
        }
#pragma unroll
        for (int i2 = 0; i2 < 4; ++i2) {
          red[wv * 2 + 0][(drb + i2) * 16 + lb] = g0[i2];
          red[wv * 2 + 1][(drb + i2) * 16 + lb] = g1[i2];
        }
        __syncthreads();
        if (tid < 128) {
          const int be = tid >> 3, du = tid & 7, ju = v * 8 + du;
          float sg[4] = {bs0, bs1, bs2, bs3};
#pragma unroll
          for (int g = 0; g < 4; ++g) {
            int c = g * 8 + du, tt = c >> 4, cc = c & 15;
            float acc = 0.f;
#pragma unroll
            for (int w2 = 0; w2 < 4; ++w2) acc += red[w2 * 2 + tt][be * 16 + cc];
            sg[g] += acc;
          }
          float I = sigm(sg[0]), F = sigm(sg[1]), G = tanh_f(sg[2]), O = sigm(sg[3]);
          c1 = F * c1 + I * G;
          float h1v = O * tanh_f(c1);
          u16 hb = f2bf(h1v);
          h1b[wh1s * 8192 + be * 512 + ju] = hb;
          Hdec[(size_t)((t << 4) + be) * 512 + ju] = hb;
        }
      }
      if (s < 64) flagbar(flags, bid, s + 1);
    }
  }
}

// ---------------------------------------------------------------- joint
// out[b][t][u][n] = tanh(enc_p[b,t,:]+dec_p[u,b,:]) @ W_out^T + b_out
// M-tile 128 rows (8t x 16u), N padded 640, mfma 32x32x16, waves 2Mx4N
__global__ __launch_bounds__(512) void joint_kernel(
    const float* __restrict__ enc_p,   // [16*200][512]
    const float* __restrict__ dec_p,   // [64*16][512]  row = u*16+b
    const u16* __restrict__ Wshuf,     // [32][20][64][8] bf16
    const float* __restrict__ boutp,   // [640]
    float* __restrict__ out)
{
  __shared__ int4 wlds[2560];   // 40960 B: 2 k16-steps x 20 tiles x 64 lanes x 16B
  __shared__ int4 zlds[512];    // 8192 B:  z chunk 128 rows x 32 k, fragment-shuffled
  int bid = blockIdx.x;
  int b = bid / 100, rem = bid % 100;
  int tb = rem >> 2, ub = rem & 3;
  int tid = threadIdx.x, wv = tid >> 6, l = tid & 63;
  int mv = wv >> 2, nv = wv & 3;
  int ln31 = l & 31, lh = l >> 5;
  f32x16 acc[2][5];
#pragma unroll
  for (int j = 0; j < 5; ++j) {
    float bv = boutp[(nv * 5 + j) * 32 + ln31];
#pragma unroll
    for (int g = 0; g < 16; ++g) { acc[0][j][g] = bv; acc[1][j][g] = bv; }
  }
  int zr = tid & 127, zg = tid >> 7;
  const float* er = enc_p + (size_t)(b * 200 + tb * 8 + (zr >> 4)) * 512 + zg * 8;
  const float* dr = dec_p + (size_t)((ub * 16 + (zr & 15)) * 16 + b) * 512 + zg * 8;
  int zslot = ((zg >> 1) * 4 + (zr >> 5)) * 64 + ((zg & 1) << 5) + (zr & 31);
  const int4* gW = (const int4*)Wshuf;
  for (int c = 0; c < 16; ++c) {
    // stage W chunk (reg->LDS)
#pragma unroll
    for (int s = 0; s < 5; ++s)
      wlds[s * 512 + tid] = gW[c * 2560 + s * 512 + tid];
    // build z chunk: each thread 8 k-contiguous elems of one row
    {
      int k0 = c * 32;
      float4 e0 = *(const float4*)(er + k0);
      float4 e1 = *(const float4*)(er + k0 + 4);
      float4 d0 = *(const float4*)(dr + k0);
      float4 d1 = *(const float4*)(dr + k0 + 4);
      u16 q0 = f2bf(tanh_f(e0.x + d0.x)), q1 = f2bf(tanh_f(e0.y + d0.y));
      u16 q2 = f2bf(tanh_f(e0.z + d0.z)), q3 = f2bf(tanh_f(e0.w + d0.w));
      u16 q4 = f2bf(tanh_f(e1.x + d1.x)), q5 = f2bf(tanh_f(e1.y + d1.y));
      u16 q6 = f2bf(tanh_f(e1.z + d1.z)), q7 = f2bf(tanh_f(e1.w + d1.w));
      int4 pk;
      pk.x = (int)q0 | ((int)q1 << 16);
      pk.y = (int)q2 | ((int)q3 << 16);
      pk.z = (int)q4 | ((int)q5 << 16);
      pk.w = (int)q6 | ((int)q7 << 16);
      zlds[zslot] = pk;
    }
    __syncthreads();
#pragma unroll
    for (int ks = 0; ks < 2; ++ks) {
      short8 aA = *(const short8*)&zlds[(ks * 4 + 2 * mv + 0) * 64 + l];
      short8 aB = *(const short8*)&zlds[(ks * 4 + 2 * mv + 1) * 64 + l];
#pragma unroll
      for (int j = 0; j < 5; ++j) {
        short8 bw = *(const short8*)&wlds[(ks * 20 + nv * 5 + j) * 64 + l];
        acc[0][j] = __builtin_amdgcn_mfma_f32_32x32x16_bf16(aA, bw, acc[0][j], 0, 0, 0);
        acc[1][j] = __builtin_amdgcn_mfma_f32_32x32x16_bf16(aB, bw, acc[1][j], 0, 0, 0);
      }
    }
    __syncthreads();
  }
  // epilogue: D[row][col]: col = lane&31, row = (g&3) + 8*(g>>2) + 4*(lane>>5)
#pragma unroll
  for (int ab = 0; ab < 2; ++ab) {
#pragma unroll
    for (int j = 0; j < 5; ++j) {
      int n = (nv * 5 + j) * 32 + ln31;
      if (n < 600) {
        int rbase = mv * 64 + ab * 32 + 4 * lh;
#pragma unroll
        for (int g = 0; g < 16; ++g) {
          int r = rbase + (g & 3) + ((g >> 2) << 3);
          int tt = tb * 8 + (r >> 4), uu = ub * 16 + (r & 15);
          out[(size_t)((b * 200 + tt) * 64 + uu) * 600 + n] = acc[ab][j][g];
        }
      }
    }
  }
}

// ---------------------------------------------------------------- host
extern "C" void kernel_launch(void* const* d_in, const int* in_sizes, int n_in,
                              void* d_out, int out_size, void* d_ws, size_t ws_size,
                              hipStream_t stream) {
  const float* hs_pad = (const float*)d_in[0];
  const int*   ys     = (const int*)d_in[1];
  const float* embed  = (const float*)d_in[2];
  const float* W_ih0  = (const float*)d_in[3];
  const float* W_hh0  = (const float*)d_in[4];
  const float* b_ih0  = (const float*)d_in[5];
  const float* b_hh0  = (const float*)d_in[6];
  const float* W_ih1  = (const float*)d_in[7];
  const float* W_hh1  = (const float*)d_in[8];
  const float* b_ih1  = (const float*)d_in[9];
  const float* b_hh1  = (const float*)d_in[10];
  const float* W_enc  = (const float*)d_in[11];
  const float* b_enc  = (const float*)d_in[12];
  const float* W_dec  = (const float*)d_in[13];
  const float* W_out  = (const float*)d_in[14];
  const float* b_out  = (const float*)d_in[15];
  float* out = (float*)d_out;

  uint8_t* ws = (uint8_t*)d_ws;
  size_t off = 0;
  auto alloc = [&](size_t bytes) -> void* {
    void* p = ws + off;
    off = (off + bytes + 255) & ~(size_t)255;
    return p;
  };
  int* flags    = (int*)alloc(8192);                     // 128 slots x 64B
  u16* h0buf    = (u16*)alloc(2 * 16 * 512 * 2);         // 32768 B
  u16* h1buf    = (u16*)alloc(2 * 16 * 512 * 2);         // 32768 B
  u16* Hdec     = (u16*)alloc(64 * 16 * 512 * 2);        // 1 MB
  float* Xg0    = (float*)alloc(1024 * 2048 * 4);        // 8 MB
  float* enc_p  = (float*)alloc(3200 * 512 * 4);         // 6.5 MB
  float* dec_p  = (float*)alloc(1024 * 512 * 4);         // 2 MB
  u16* Wih0b    = (u16*)alloc(2048 * 512 * 2);
  u16* Whh0b    = (u16*)alloc(2048 * 512 * 2);
  u16* Wih1b    = (u16*)alloc(2048 * 512 * 2);
  u16* Whh1b    = (u16*)alloc(2048 * 512 * 2);
  u16* Wencb    = (u16*)alloc(512 * 512 * 2);
  u16* Wdecb    = (u16*)alloc(512 * 512 * 2);
  u16* embedb   = (u16*)alloc(600 * 512 * 2);
  u16* hsb      = (u16*)alloc(3200 * 512 * 2);
  u16* Wshufb   = (u16*)alloc(32 * 20 * 64 * 8 * 2);
  float* bsum0  = (float*)alloc(2048 * 4);
  float* bsum1  = (float*)alloc(2048 * 4);
  float* boutp  = (float*)alloc(640 * 4);

  // flags: WG slots (0..95) zero, padding slots (96..127) huge; h-state zero
  (void)hipMemsetAsync(flags, 0, 96 * 64, stream);
  (void)hipMemsetAsync((uint8_t*)flags + 96 * 64, 0x7f, 32 * 64, stream);
  (void)hipMemsetAsync(h0buf, 0, 65536, stream);

  prep_kernel<<<2048, 256, 0, stream>>>(
      W_ih0, W_hh0, W_ih1, W_hh1, W_enc, W_dec, W_out, embed, hs_pad,
      b_ih0, b_hh0, b_ih1, b_hh1, b_out,
      Wih0b, Whh0b, Wih1b, Whh1b, Wencb, Wdecb, embedb, hsb, Wshufb,
      bsum0, bsum1, boutp);

  // Xg0 = embed[ys] @ W_ih0^T + (b_ih0 + b_hh0), rows m = u*16+b
  dim3 g1(16, 32);
  gemm_bf16<<<g1, 256, 0, stream>>>(embedb, Wih0b, ys, bsum0, Xg0, 2048, 1);
  // enc_p = hs @ W_enc^T + b_enc
  dim3 g2(50, 8);
  gemm_bf16<<<g2, 256, 0, stream>>>(hsb, Wencb, nullptr, b_enc, enc_p, 512, 0);
  // sequential 2-layer LSTM (layer-pipelined, flag-array barrier)
  lstm_kernel<<<NWGT, 256, 0, stream>>>(Xg0, Whh0b, Wih1b, Whh1b, bsum1, h0buf, h1buf, Hdec, flags);
  // dec_p = Hdec @ W_dec^T
  dim3 g3(16, 8);
  gemm_bf16<<<g3, 256, 0, stream>>>(Hdec, Wdecb, nullptr, nullptr, dec_p, 512, 0);
  // big fused joint
  joint_kernel<<<1600, 512, 0, stream>>>(enc_p, dec_p, Wshufb, boutp, out);
}